// Round 4
// baseline (50.676 us; speedup 1.0000x reference)
//
#include <hip/hip_runtime.h>
#include <math.h>

#define FAR_DIST 1e10f
#define EPS 1e-10f

typedef float f32x4 __attribute__((ext_vector_type(4)));

// 4 rays per 64-lane wave: 16-lane segments, 12 contiguous samples per lane
// (S=192 = 16 x 12). Segmented shfl scan (width 16) for the exclusive
// cumprod; per-lane serial prefix over the 12 owned samples.
__global__ __launch_bounds__(256) void render_kernel(
    const float* __restrict__ sigma,   // [N,S]
    const float* __restrict__ color,   // [N,S,3]
    const float* __restrict__ z_vals,  // [N,S]
    const float* __restrict__ rays,    // [N,6]
    float* __restrict__ rgb,           // [N,3]
    float* __restrict__ weights,       // [N,S]
    int N)
{
    const int S = 192;
    const int wave = threadIdx.x >> 6;
    const int lane = threadIdx.x & 63;
    const int q    = lane & 15;                 // lane within segment
    const int gw   = blockIdx.x * 4 + wave;     // global wave id
    const int n    = gw * 4 + (lane >> 4);      // ray id (one per 16-lane segment)
    if (n >= N) return;

    // ray direction norm (segment-uniform broadcast load)
    const float* rp = rays + (size_t)n * 6;
    const float dn = sqrtf(rp[0] * rp[0] + rp[1] * rp[1] + rp[2] * rp[2]);

    const int s0 = q * 12;
    const float* zb = z_vals + (size_t)n * S + s0;
    const float* sb = sigma  + (size_t)n * S + s0;

    alignas(16) float z[12];
    alignas(16) float sg[12];
    #pragma unroll
    for (int j = 0; j < 3; ++j) {
        ((f32x4*)z)[j]  = *(const f32x4*)(zb + 4 * j);
        ((f32x4*)sg)[j] = *(const f32x4*)(sb + 4 * j);
    }

    // next lane's first z (for my last interval); q==15 uses FAR
    const float znext = __shfl_down(z[0], 1, 16);

    float d[12];
    #pragma unroll
    for (int k = 0; k < 11; ++k) d[k] = z[k + 1] - z[k];
    d[11] = (q == 15) ? FAR_DIST : (znext - z[11]);

    // e = exp(-sigma*dist) = 1-alpha ; x = e + EPS ; P = prod(x)
    float x[12], a[12];
    float P = 1.0f;
    #pragma unroll
    for (int k = 0; k < 12; ++k) {
        const float e = __expf(-sg[k] * d[k] * dn);
        a[k] = 1.0f - e;
        x[k] = e + EPS;
        P *= x[k];
    }

    // segmented (width-16) inclusive scan of lane products
    float scan = P;
    #pragma unroll
    for (int off = 1; off < 16; off <<= 1) {
        const float v = __shfl_up(scan, off, 16);
        if (q >= off) scan *= v;
    }
    float T = __shfl_up(scan, 1, 16);
    if (q == 0) T = 1.0f;

    // per-sample transmittance, weights
    alignas(16) float w[12];
    #pragma unroll
    for (int k = 0; k < 12; ++k) {
        w[k] = a[k] * T;
        T *= x[k];
    }

    float* wb = weights + (size_t)n * S + s0;
    #pragma unroll
    for (int j = 0; j < 3; ++j)
        __builtin_nontemporal_store(((const f32x4*)w)[j], (f32x4*)(wb + 4 * j));

    // rgb accumulation: 36 floats (12 samples x rgb) as 9 x 16B loads
    alignas(16) float c[36];
    const float* cb = color + ((size_t)n * S + s0) * 3;
    #pragma unroll
    for (int j = 0; j < 9; ++j) ((f32x4*)c)[j] = *(const f32x4*)(cb + 4 * j);

    float r = 0.f, g = 0.f, b = 0.f;
    #pragma unroll
    for (int k = 0; k < 12; ++k) {
        r += w[k] * c[3 * k + 0];
        g += w[k] * c[3 * k + 1];
        b += w[k] * c[3 * k + 2];
    }

    // segmented reduce (width 16)
    #pragma unroll
    for (int off = 8; off >= 1; off >>= 1) {
        r += __shfl_xor(r, off, 16);
        g += __shfl_xor(g, off, 16);
        b += __shfl_xor(b, off, 16);
    }
    if (q == 0) {
        __builtin_nontemporal_store(r, rgb + n * 3 + 0);
        __builtin_nontemporal_store(g, rgb + n * 3 + 1);
        __builtin_nontemporal_store(b, rgb + n * 3 + 2);
    }
}

extern "C" void kernel_launch(void* const* d_in, const int* in_sizes, int n_in,
                              void* d_out, int out_size, void* d_ws, size_t ws_size,
                              hipStream_t stream) {
    const float* sigma  = (const float*)d_in[0];  // [N,S,1]
    const float* color  = (const float*)d_in[1];  // [N,S,3]
    const float* z_vals = (const float*)d_in[2];  // [N,S]
    const float* rays   = (const float*)d_in[3];  // [N,6]

    const int N = in_sizes[3] / 6;                // 65536
    float* rgb     = (float*)d_out;               // [N,3]
    float* weights = (float*)d_out + (size_t)N * 3;  // [N,S,1]

    // 16 rays per 256-thread block (4 waves x 4 rays)
    const int blocks = (N + 15) / 16;
    render_kernel<<<blocks, 256, 0, stream>>>(sigma, color, z_vals, rays,
                                              rgb, weights, N);
}

// Round 5
// 48.325 us; speedup vs baseline: 1.0486x; 1.0486x over previous
//
#include <hip/hip_runtime.h>
#include <math.h>

#define FAR_DIST 1e10f
#define EPS 1e-10f

typedef float f32x4 __attribute__((ext_vector_type(4)));

// DPP cross-lane helpers (pure VALU — avoids the ds_bpermute/LDS pipe).
// CTRL: 0x111/0x112/0x114/0x118 = row_shr:1/2/4/8, 0x142 = row_bcast15,
// 0x143 = row_bcast31. Masked / out-of-bound lanes receive `old` (identity).
template<int CTRL, int RMASK>
__device__ __forceinline__ float dpp_mul(float s) {
    int t = __builtin_amdgcn_update_dpp(__float_as_int(1.0f), __float_as_int(s),
                                        CTRL, RMASK, 0xf, false);
    return s * __int_as_float(t);
}
template<int CTRL, int RMASK>
__device__ __forceinline__ float dpp_add(float s) {
    int t = __builtin_amdgcn_update_dpp(0, __float_as_int(s),
                                        CTRL, RMASK, 0xf, false);
    return s + __int_as_float(t);
}

__device__ __forceinline__ float wave_iscan_prod(float s) {
    s = dpp_mul<0x111, 0xf>(s);   // row_shr:1
    s = dpp_mul<0x112, 0xf>(s);   // row_shr:2
    s = dpp_mul<0x114, 0xf>(s);   // row_shr:4
    s = dpp_mul<0x118, 0xf>(s);   // row_shr:8  -> inclusive within each row16
    s = dpp_mul<0x142, 0xa>(s);   // row_bcast15 -> rows 1,3
    s = dpp_mul<0x143, 0xc>(s);   // row_bcast31 -> rows 2,3
    return s;                     // full wave64 inclusive product scan
}
__device__ __forceinline__ float wave_reduce_sum(float s) {
    s = dpp_add<0x111, 0xf>(s);
    s = dpp_add<0x112, 0xf>(s);
    s = dpp_add<0x114, 0xf>(s);
    s = dpp_add<0x118, 0xf>(s);
    s = dpp_add<0x142, 0xa>(s);
    s = dpp_add<0x143, 0xc>(s);
    return s;                     // lane 63 holds the wave total
}

// One 64-lane wave per ray; lanes 0..47 each own 4 contiguous samples
// (S=192 = 48 x 4). 16B vector loads/stores; DPP scan/reduce.
__global__ __launch_bounds__(256) void render_kernel(
    const float* __restrict__ sigma,   // [N,S]
    const float* __restrict__ color,   // [N,S,3]
    const float* __restrict__ z_vals,  // [N,S]
    const float* __restrict__ rays,    // [N,6]
    float* __restrict__ rgb,           // [N,3]
    float* __restrict__ weights,       // [N,S]
    int N)
{
    const int S = 192;
    const int wave = threadIdx.x >> 6;
    const int lane = threadIdx.x & 63;
    const int n = blockIdx.x * 4 + wave;
    if (n >= N) return;

    const bool active = (lane < 48);
    const int s0 = lane * 4;

    // ray direction norm (broadcast load)
    const float rx = rays[n * 6 + 0];
    const float ry = rays[n * 6 + 1];
    const float rz = rays[n * 6 + 2];
    const float dn = sqrtf(rx * rx + ry * ry + rz * rz);

    const float* zb = z_vals + (size_t)n * S;
    f32x4 z4 = (f32x4)(0.f);
    if (active) z4 = *(const f32x4*)(zb + s0);

    // next lane's first z (for my last interval); lane 47 uses FAR
    const float znext = __shfl_down(z4.x, 1, 64);

    const float d0 = (z4.y - z4.x) * dn;
    const float d1 = (z4.z - z4.y) * dn;
    const float d2 = (z4.w - z4.z) * dn;
    const float d3 = (lane == 47) ? FAR_DIST * dn : (znext - z4.w) * dn;

    f32x4 sg = (f32x4)(0.f);
    if (active) sg = *(const f32x4*)(sigma + (size_t)n * S + s0);

    // e = exp(-sigma*dist) = 1 - alpha ; x = e + EPS
    const float e0 = __expf(-sg.x * d0);
    const float e1 = __expf(-sg.y * d1);
    const float e2 = __expf(-sg.z * d2);
    const float e3 = __expf(-sg.w * d3);
    const float x0 = e0 + EPS;
    const float x1 = e1 + EPS;
    const float x2 = e2 + EPS;
    const float x3 = e3 + EPS;

    // lane product; inactive lanes contribute identity
    const float P = active ? (x0 * x1) * (x2 * x3) : 1.0f;

    // wave inclusive scan (DPP, VALU-only), then exclusive via one shfl_up
    const float scan = wave_iscan_prod(P);
    float Texcl = __shfl_up(scan, 1, 64);
    if (lane == 0) Texcl = 1.0f;

    // per-sample transmittance and weights
    const float T0 = Texcl;
    const float T1 = T0 * x0;
    const float T2 = T1 * x1;
    const float T3 = T2 * x2;
    const float w0 = (1.0f - e0) * T0;
    const float w1 = (1.0f - e1) * T1;
    const float w2 = (1.0f - e2) * T2;
    const float w3 = (1.0f - e3) * T3;

    if (active) {
        f32x4 w4;
        w4.x = w0; w4.y = w1; w4.z = w2; w4.w = w3;
        __builtin_nontemporal_store(w4, (f32x4*)(weights + (size_t)n * S + s0));
    }

    // rgb accumulation: 12 colors per active lane as 3 x 16B vectors
    float r = 0.f, g = 0.f, b = 0.f;
    if (active) {
        const float* cb = color + ((size_t)n * S + s0) * 3;
        const f32x4 c0 = *(const f32x4*)(cb + 0);   // s0.rgb, s1.r
        const f32x4 c1 = *(const f32x4*)(cb + 4);   // s1.gb, s2.rg
        const f32x4 c2 = *(const f32x4*)(cb + 8);   // s2.b, s3.rgb
        r = w0 * c0.x + w1 * c0.w + w2 * c1.z + w3 * c2.y;
        g = w0 * c0.y + w1 * c1.x + w2 * c1.w + w3 * c2.z;
        b = w0 * c0.z + w1 * c1.y + w2 * c2.x + w3 * c2.w;
    }

    // DPP reduce; lane 63 ends with the wave total and stores it
    r = wave_reduce_sum(r);
    g = wave_reduce_sum(g);
    b = wave_reduce_sum(b);
    if (lane == 63) {
        __builtin_nontemporal_store(r, rgb + n * 3 + 0);
        __builtin_nontemporal_store(g, rgb + n * 3 + 1);
        __builtin_nontemporal_store(b, rgb + n * 3 + 2);
    }
}

extern "C" void kernel_launch(void* const* d_in, const int* in_sizes, int n_in,
                              void* d_out, int out_size, void* d_ws, size_t ws_size,
                              hipStream_t stream) {
    const float* sigma  = (const float*)d_in[0];  // [N,S,1]
    const float* color  = (const float*)d_in[1];  // [N,S,3]
    const float* z_vals = (const float*)d_in[2];  // [N,S]
    const float* rays   = (const float*)d_in[3];  // [N,6]

    const int N = in_sizes[3] / 6;                // 65536
    float* rgb     = (float*)d_out;               // [N,3]
    float* weights = (float*)d_out + (size_t)N * 3;  // [N,S,1]

    const int blocks = (N + 3) / 4;               // 4 rays (waves) per 256-thread block
    render_kernel<<<blocks, 256, 0, stream>>>(sigma, color, z_vals, rays,
                                              rgb, weights, N);
}